// Round 7
// baseline (1185.946 us; speedup 1.0000x reference)
//
#include <hip/hip_runtime.h>
#include <hip/hip_bf16.h>
#include <math.h>

#define TT 2048
#define HID 2560
#define NH 40
#define NOPE 64
#define ROPE 32
#define VDIM 64
#define QLORA 768
#define KVLORA 256
#define DQK 288            // KVLORA + ROPE
#define QHD 96             // NOPE + ROPE
#define EPS 1e-5f
#define THETA 10000.0f

typedef __attribute__((ext_vector_type(8))) short bf16x8;
typedef __attribute__((ext_vector_type(4))) float f32x4;
typedef __attribute__((address_space(1))) const void* gas_t;
typedef __attribute__((address_space(3))) void* las_t;

static __device__ __forceinline__ ushort f2bf(float x) {
    __hip_bfloat16 b = __float2bfloat16(x);
    return *reinterpret_cast<ushort*>(&b);
}

// ---------------- flat fp32 -> bf16 cast ----------------
__global__ __launch_bounds__(256) void cast_bf16(const float* __restrict__ x,
                                                 ushort* __restrict__ y, int n) {
    int i = (blockIdx.x * 256 + threadIdx.x) * 4;
    if (i + 3 < n) {
        float4 v = *(const float4*)(x + i);
        y[i]     = f2bf(v.x);
        y[i + 1] = f2bf(v.y);
        y[i + 2] = f2bf(v.z);
        y[i + 3] = f2bf(v.w);
    }
}

// ------------- transpose + cast: w (K x N fp32) -> wt (N x K bf16) -------------
__global__ __launch_bounds__(256) void transpose_cast(const float* __restrict__ w,
                                                      ushort* __restrict__ wt,
                                                      int K, int N) {
    __shared__ float tile[32][33];
    int bn = blockIdx.x * 32, bk = blockIdx.y * 32;
    int tx = threadIdx.x % 32, ty = threadIdx.x / 32;   // 32 x 8
    #pragma unroll
    for (int i = 0; i < 32; i += 8) {
        int k = bk + ty + i, n = bn + tx;
        if (k < K && n < N) tile[ty + i][tx] = w[(size_t)k * N + n];
    }
    __syncthreads();
    #pragma unroll
    for (int i = 0; i < 32; i += 8) {
        int n = bn + ty + i, k = bk + tx;
        if (n < N && k < K) wt[(size_t)n * K + k] = f2bf(tile[tx][ty + i]);
    }
}

// ------- bf16 MFMA GEMM (m97 structure): C(MxN,f32) = A(MxK,bf16) @ Bt(NxK,bf16)^T -------
__global__ __launch_bounds__(256, 2) void gemm_bf16(const ushort* __restrict__ A,
                                                    const ushort* __restrict__ Bt,
                                                    float* __restrict__ C,
                                                    int M, int N, int K) {
    __shared__ ushort As[128 * 32];
    __shared__ ushort Bs[128 * 32];
    const int tid  = threadIdx.x;
    const int lane = tid & 63;
    const int wv   = tid >> 6;
    const int col  = lane & 15;
    const int quad = lane >> 4;
    const int m0 = blockIdx.y * 128, n0 = blockIdx.x * 128;
    const int wr = (wv >> 1) * 64, wc = (wv & 1) * 64;

    f32x4 acc[4][4];
    #pragma unroll
    for (int i = 0; i < 4; i++)
        #pragma unroll
        for (int j = 0; j < 4; j++) acc[i][j] = (f32x4){0.f, 0.f, 0.f, 0.f};

    for (int k0 = 0; k0 < K; k0 += 32) {
        #pragma unroll
        for (int j = 0; j < 2; j++) {
            int slot = wv * 128 + j * 64 + lane;     // 0..511
            int row  = slot >> 2;
            int ch   = slot & 3;
            const ushort* ga = A + (size_t)(m0 + row) * K + k0 + ch * 8;
            __builtin_amdgcn_global_load_lds((gas_t)ga, (las_t)(As + slot * 8), 16, 0, 0);
            int brow = n0 + row; if (brow >= N) brow = N - 1;   // clamp (edge tiles)
            const ushort* gb = Bt + (size_t)brow * K + k0 + ch * 8;
            __builtin_amdgcn_global_load_lds((gas_t)gb, (las_t)(Bs + slot * 8), 16, 0, 0);
        }
        __syncthreads();
        bf16x8 af[4], bfr[4];
        #pragma unroll
        for (int i = 0; i < 4; i++)
            af[i] = *(const bf16x8*)(As + (wr + i * 16 + col) * 32 + quad * 8);
        #pragma unroll
        for (int j = 0; j < 4; j++)
            bfr[j] = *(const bf16x8*)(Bs + (wc + j * 16 + col) * 32 + quad * 8);
        #pragma unroll
        for (int i = 0; i < 4; i++)
            #pragma unroll
            for (int j = 0; j < 4; j++)
                acc[i][j] = __builtin_amdgcn_mfma_f32_16x16x32_bf16(af[i], bfr[j], acc[i][j], 0, 0, 0);
        __syncthreads();
    }
    #pragma unroll
    for (int i = 0; i < 4; i++) {
        int gr = m0 + wr + i * 16 + quad * 4;
        #pragma unroll
        for (int j = 0; j < 4; j++) {
            int gc = n0 + wc + j * 16 + col;
            if (gc < N) {
                #pragma unroll
                for (int r = 0; r < 4; r++)
                    C[(size_t)(gr + r) * N + gc] = acc[i][j][r];
            }
        }
    }
}

// ------- 128x64-tile variant for narrow-N GEMMs (N=768, N=288): better grid occupancy -------
__global__ __launch_bounds__(256, 4) void gemm_bf16_n64(const ushort* __restrict__ A,
                                                        const ushort* __restrict__ Bt,
                                                        float* __restrict__ C,
                                                        int M, int N, int K) {
    __shared__ ushort As[128 * 32];
    __shared__ ushort Bs[64 * 32];
    const int tid  = threadIdx.x;
    const int lane = tid & 63;
    const int wv   = tid >> 6;
    const int col  = lane & 15;
    const int quad = lane >> 4;
    const int m0 = blockIdx.y * 128, n0 = blockIdx.x * 64;
    const int wr = wv * 32;

    f32x4 acc[2][4];
    #pragma unroll
    for (int i = 0; i < 2; i++)
        #pragma unroll
        for (int j = 0; j < 4; j++) acc[i][j] = (f32x4){0.f, 0.f, 0.f, 0.f};

    for (int k0 = 0; k0 < K; k0 += 32) {
        #pragma unroll
        for (int j = 0; j < 2; j++) {                // A: 512 slots, 2/thread
            int slot = j * 256 + tid;
            int row  = slot >> 2;
            int ch   = slot & 3;
            const ushort* ga = A + (size_t)(m0 + row) * K + k0 + ch * 8;
            __builtin_amdgcn_global_load_lds((gas_t)ga, (las_t)(As + slot * 8), 16, 0, 0);
        }
        {                                            // B: 256 slots, 1/thread
            int row = tid >> 2;
            int ch  = tid & 3;
            int brow = n0 + row; if (brow >= N) brow = N - 1;
            const ushort* gb = Bt + (size_t)brow * K + k0 + ch * 8;
            __builtin_amdgcn_global_load_lds((gas_t)gb, (las_t)(Bs + tid * 8), 16, 0, 0);
        }
        __syncthreads();
        bf16x8 af[2], bfr[4];
        #pragma unroll
        for (int i = 0; i < 2; i++)
            af[i] = *(const bf16x8*)(As + (wr + i * 16 + col) * 32 + quad * 8);
        #pragma unroll
        for (int j = 0; j < 4; j++)
            bfr[j] = *(const bf16x8*)(Bs + (j * 16 + col) * 32 + quad * 8);
        #pragma unroll
        for (int i = 0; i < 2; i++)
            #pragma unroll
            for (int j = 0; j < 4; j++)
                acc[i][j] = __builtin_amdgcn_mfma_f32_16x16x32_bf16(af[i], bfr[j], acc[i][j], 0, 0, 0);
        __syncthreads();
    }
    #pragma unroll
    for (int i = 0; i < 2; i++) {
        int gr = m0 + wr + i * 16 + quad * 4;
        #pragma unroll
        for (int j = 0; j < 4; j++) {
            int gc = n0 + j * 16 + col;
            if (gc < N) {
                #pragma unroll
                for (int r = 0; r < 4; r++)
                    C[(size_t)(gr + r) * N + gc] = acc[i][j][r];
            }
        }
    }
}

// ---------------- RMS norm: fp32 in, bf16 out ----------------
__global__ __launch_bounds__(256) void rms_qa(const float* __restrict__ x,
                                              const float* __restrict__ g,
                                              ushort* __restrict__ y) {
    int t = blockIdx.x, tid = threadIdx.x;
    __shared__ float red[256];
    __shared__ float s_inv;
    const float* row = x + (size_t)t * QLORA;
    float ss = 0.f;
    for (int i = tid; i < QLORA; i += 256) { float v = row[i]; ss += v * v; }
    red[tid] = ss; __syncthreads();
    for (int s = 128; s > 0; s >>= 1) { if (tid < s) red[tid] += red[tid + s]; __syncthreads(); }
    if (tid == 0) s_inv = rsqrtf(red[0] / (float)QLORA + EPS);
    __syncthreads();
    float si = s_inv;
    ushort* orow = y + (size_t)t * QLORA;
    for (int i = tid; i < QLORA; i += 256) orow[i] = f2bf(row[i] * si * g[i]);
}

// ------- latent post: RMS first 256, RoPE last 32 -> bf16 kin_bf (T x 288) -------
__global__ __launch_bounds__(256) void kin_post(const float* __restrict__ kin,
                                                const float* __restrict__ g,
                                                const int* __restrict__ positions,
                                                ushort* __restrict__ kin_bf) {
    int t = blockIdx.x, tid = threadIdx.x;
    __shared__ float red[256];
    __shared__ float s_inv;
    const float* row = kin + (size_t)t * DQK;
    float v = row[tid];
    red[tid] = v * v; __syncthreads();
    for (int s = 128; s > 0; s >>= 1) { if (tid < s) red[tid] += red[tid + s]; __syncthreads(); }
    if (tid == 0) s_inv = rsqrtf(red[0] / (float)KVLORA + EPS);
    __syncthreads();
    ushort* orow = kin_bf + (size_t)t * DQK;
    orow[tid] = f2bf(v * s_inv * g[tid]);
    if (tid < 16) {
        float pos = (float)positions[t];
        float freq = powf(THETA, -(float)tid / 16.0f);
        float f = pos * freq;
        float c = cosf(f), s = sinf(f);
        float x1 = row[KVLORA + tid], x2 = row[KVLORA + 16 + tid];
        orow[KVLORA + tid]      = f2bf(x1 * c - x2 * s);
        orow[KVLORA + 16 + tid] = f2bf(x2 * c + x1 * s);
    }
}

// --- q_in build (tiled: 16 t-rows per block, w_kc[h] read once per block) ---
#define QTB 16
__global__ __launch_bounds__(256) void build_qin(const float* __restrict__ q,
                                                 const float* __restrict__ w_kc,
                                                 const int* __restrict__ positions,
                                                 ushort* __restrict__ qin) {
    int tb = blockIdx.x * QTB, h = blockIdx.y, tid = threadIdx.x;
    const float scale = 0.10206207261596577f;   // 1/sqrt(96), folded into Q
    __shared__ float qn[QTB][NOPE];
    __shared__ float qp[QTB][ROPE];
    // load 16 q rows (96 floats each)
    for (int i = tid; i < QTB * QHD; i += 256) {
        int r = i / QHD, cidx = i % QHD;
        float v = q[(size_t)(tb + r) * (NH * QHD) + h * QHD + cidx];
        if (cidx < NOPE) qn[r][cidx] = v;
        else             qp[r][cidx - NOPE] = v;
    }
    __syncthreads();
    // each thread owns one latent dim k for all 16 rows
    int k = tid;
    float acc[QTB];
    #pragma unroll
    for (int r = 0; r < QTB; r++) acc[r] = 0.f;
    const float* w = w_kc + (size_t)h * NOPE * KVLORA + k;
    for (int n = 0; n < NOPE; n++) {
        float wval = w[(size_t)n * KVLORA];
        #pragma unroll
        for (int r = 0; r < QTB; r++) acc[r] += qn[r][n] * wval;
    }
    #pragma unroll
    for (int r = 0; r < QTB; r++)
        qin[((size_t)(tb + r) * NH + h) * DQK + k] = f2bf(acc[r] * scale);
    // rope: 16 rows x 16 freqs = 256 threads
    int r = tid >> 4, fi = tid & 15;
    float pos = (float)positions[tb + r];
    float freq = powf(THETA, -(float)fi / 16.0f);
    float f = pos * freq;
    float c = cosf(f), s = sinf(f);
    float x1 = qp[r][fi], x2 = qp[r][16 + fi];
    ushort* orow = qin + ((size_t)(tb + r) * NH + h) * DQK;
    orow[KVLORA + fi]      = f2bf((x1 * c - x2 * s) * scale);
    orow[KVLORA + 16 + fi] = f2bf((x2 * c + x1 * s) * scale);
}

// ---------------- flash MFMA attention ----------------
// r4 base (256 thr, 4 waves, 1 head, KVB=32) + three fixes:
//  1. uniform-work pairing: each block runs q-tile qb_hi=1984-64x THEN qb_lo=64x
//     -> every block does exactly 68 iterations (kills the triangular tail).
//  2. T14 async-split staging: tile t+1's global loads (5 uint4 = 20 VGPR) issue
//     right after the post-stage barrier and fly across the whole compute phase.
//  3. defer-max rescale (THR=8): skip 4x exp + 64-mul of-rescale when
//     __all(mx - m_i <= 8); P bounded by e^8, normalized out by l.
#define KVB 32
#define KSTR 296
#define VSTR 40
#define PSTR 40

__global__ __launch_bounds__(256, 3) void flash_attn(const ushort* __restrict__ qin,
                                                     const ushort* __restrict__ kin,
                                                     float* __restrict__ o_lat) {
    __shared__ __align__(16) ushort lds[KVB * KSTR + 256 * VSTR + 64 * PSTR];
    ushort* krow = lds;                       // 32 x 296 (18944 B)
    ushort* vt   = lds + KVB * KSTR;          // 256 x 40 (20480 B)
    ushort* pbuf = vt + 256 * VSTR;           // 64 x 40  (5120 B)  total 44544 B

    const int tid  = threadIdx.x;
    const int lane = tid & 63;
    const int wv   = tid >> 6;
    const int col  = lane & 15;
    const int quad = lane >> 4;
    const int h    = blockIdx.y;

    const int qb_hi = (TT - 64) - (int)blockIdx.x * 64;
    const int qb_lo = (int)blockIdx.x * 64;

    // staging geometry: 32 rows x 8 chunk-groups
    const int srow = tid & 31;
    const int sgrp = tid >> 5;                // 0..7

    uint4 su[4];    // staged K/V chunks (held across compute: T14)
    uint4 sur;      // staged rope chunk (sgrp < 4 only)

#define STAGE_LOAD(S0) do {                                                     \
        const ushort* src_ = kin + (size_t)((S0) + srow) * DQK;                 \
        _Pragma("unroll")                                                       \
        for (int ci_ = 0; ci_ < 4; ci_++)                                       \
            su[ci_] = *(const uint4*)(src_ + ci_ * 64 + sgrp * 8);              \
        if (sgrp < 4) sur = *(const uint4*)(src_ + 256 + sgrp * 8);             \
    } while (0)

#define STAGE_WRITE() do {                                                      \
        _Pragma("unroll")                                                       \
        for (int ci_ = 0; ci_ < 4; ci_++) {                                     \
            int c_ = ci_ * 8 + sgrp;                                            \
            *(uint4*)(krow + srow * KSTR + c_ * 8) = su[ci_];                   \
            const ushort* up_ = (const ushort*)&su[ci_];                        \
            _Pragma("unroll")                                                   \
            for (int j_ = 0; j_ < 8; j_++)                                      \
                vt[(c_ * 8 + j_) * VSTR + srow] = up_[j_];                      \
        }                                                                       \
        if (sgrp < 4) *(uint4*)(krow + srow * KSTR + (32 + sgrp) * 8) = sur;    \
    } while (0)

    for (int ph = 0; ph < 2; ph++) {
        const int qb = ph ? qb_lo : qb_hi;
        const int rowg = qb + wv * 16 + quad * 4;   // this thread's first q-row

        bf16x8 qf[9];
        {
            const ushort* base = qin + ((size_t)(qb + wv * 16 + col) * NH + h) * DQK + quad * 8;
            #pragma unroll
            for (int k = 0; k < 9; k++) qf[k] = *(const bf16x8*)(base + k * 32);
        }

        f32x4 of[16];
        #pragma unroll
        for (int i = 0; i < 16; i++) of[i] = (f32x4){0.f, 0.f, 0.f, 0.f};
        float m_i[4] = {-1e30f, -1e30f, -1e30f, -1e30f};
        float l_i[4] = {0.f, 0.f, 0.f, 0.f};

        STAGE_LOAD(0);

        for (int s0 = 0; s0 <= qb + 32; s0 += KVB) {
            __syncthreads();                 // all waves done reading prev tile
            STAGE_WRITE();                   // waits vmcnt via reg deps
            if (s0 + KVB <= qb + 32) STAGE_LOAD(s0 + KVB);   // fly across compute
            __syncthreads();

            // ---- QK^T ----
            f32x4 sf[2];
            sf[0] = (f32x4){0.f, 0.f, 0.f, 0.f};
            sf[1] = (f32x4){0.f, 0.f, 0.f, 0.f};
            __builtin_amdgcn_s_setprio(1);
            #pragma unroll
            for (int k = 0; k < 9; k++) {
                #pragma unroll
                for (int tc = 0; tc < 2; tc++) {
                    bf16x8 bf = *(const bf16x8*)(krow + (tc * 16 + col) * KSTR + k * 32 + quad * 8);
                    sf[tc] = __builtin_amdgcn_mfma_f32_16x16x32_bf16(qf[k], bf, sf[tc], 0, 0, 0);
                }
            }
            __builtin_amdgcn_s_setprio(0);

            // causal mask (always on: diagonal spans the last two 32-tiles)
            #pragma unroll
            for (int tc = 0; tc < 2; tc++)
                #pragma unroll
                for (int r = 0; r < 4; r++)
                    if (s0 + tc * 16 + col > rowg + r) sf[tc][r] = -1e30f;

            // ---- tile max ----
            float mx[4];
            #pragma unroll
            for (int r = 0; r < 4; r++) {
                float m = fmaxf(sf[0][r], sf[1][r]);
                m = fmaxf(m, __shfl_xor(m, 1));
                m = fmaxf(m, __shfl_xor(m, 2));
                m = fmaxf(m, __shfl_xor(m, 4));
                m = fmaxf(m, __shfl_xor(m, 8));
                mx[r] = m;
            }
            // ---- defer-max (T13): skip rescale when max grows <= 8 ----
            int okl = (mx[0] - m_i[0] <= 8.f) && (mx[1] - m_i[1] <= 8.f) &&
                      (mx[2] - m_i[2] <= 8.f) && (mx[3] - m_i[3] <= 8.f);
            int ok = __all(okl);
            float mref[4], alpha[4];
            if (ok) {
                #pragma unroll
                for (int r = 0; r < 4; r++) mref[r] = m_i[r];
            } else {
                #pragma unroll
                for (int r = 0; r < 4; r++) {
                    mref[r] = fmaxf(m_i[r], mx[r]);
                    alpha[r] = __expf(m_i[r] - mref[r]);
                    m_i[r] = mref[r];
                }
            }
            float rsum[4];
            #pragma unroll
            for (int r = 0; r < 4; r++) {
                float s = 0.f;
                #pragma unroll
                for (int tc = 0; tc < 2; tc++) {
                    float p = __expf(sf[tc][r] - mref[r]);
                    sf[tc][r] = p;
                    s += p;
                }
                s += __shfl_xor(s, 1);
                s += __shfl_xor(s, 2);
                s += __shfl_xor(s, 4);
                s += __shfl_xor(s, 8);
                rsum[r] = s;
            }
            if (ok) {
                #pragma unroll
                for (int r = 0; r < 4; r++) l_i[r] += rsum[r];
            } else {
                #pragma unroll
                for (int r = 0; r < 4; r++) l_i[r] = l_i[r] * alpha[r] + rsum[r];
                #pragma unroll
                for (int i = 0; i < 16; i++)
                    #pragma unroll
                    for (int r = 0; r < 4; r++) of[i][r] *= alpha[r];
            }

            // ---- P -> pbuf (per-wave private rows: no barrier needed) ----
            #pragma unroll
            for (int tc = 0; tc < 2; tc++)
                #pragma unroll
                for (int r = 0; r < 4; r++)
                    pbuf[(wv * 16 + quad * 4 + r) * PSTR + tc * 16 + col] = f2bf(sf[tc][r]);
            bf16x8 pa = *(const bf16x8*)(pbuf + (wv * 16 + col) * PSTR + quad * 8);

            // ---- PV ----
            __builtin_amdgcn_s_setprio(1);
            #pragma unroll
            for (int nt = 0; nt < 16; nt++) {
                bf16x8 vb = *(const bf16x8*)(vt + (nt * 16 + col) * VSTR + quad * 8);
                of[nt] = __builtin_amdgcn_mfma_f32_16x16x32_bf16(pa, vb, of[nt], 0, 0, 0);
            }
            __builtin_amdgcn_s_setprio(0);
        }
        #pragma unroll
        for (int r = 0; r < 4; r++) {
            float inv = 1.0f / l_i[r];
            int row = qb + wv * 16 + quad * 4 + r;
            float* dst = o_lat + ((size_t)row * NH + h) * KVLORA + col;
            #pragma unroll
            for (int nt = 0; nt < 16; nt++) dst[nt * 16] = of[nt][r] * inv;
        }
    }
#undef STAGE_LOAD
#undef STAGE_WRITE
}

// ------- o_bf = o_lat @ w_vc[h] (tiled: 16 t-rows per block, w_vc[h] read once) -------
__global__ __launch_bounds__(256) void ogemm(const float* __restrict__ o_lat,
                                             const float* __restrict__ w_vc,
                                             ushort* __restrict__ o) {
    int tb = blockIdx.x * 16, h = blockIdx.y, tid = threadIdx.x;
    __shared__ float ol[16][KVLORA];
    for (int i = tid; i < 16 * KVLORA; i += 256) {
        int r = i >> 8, k = i & 255;
        ol[r][k] = o_lat[((size_t)(tb + r) * NH + h) * KVLORA + k];
    }
    __syncthreads();
    int v = tid & 63, r0 = tid >> 6;       // 4 rows/thread: r0, r0+4, r0+8, r0+12
    float acc[4] = {0.f, 0.f, 0.f, 0.f};
    const float* w = w_vc + (size_t)h * KVLORA * VDIM + v;
    for (int k = 0; k < KVLORA; k++) {
        float wval = w[(size_t)k * VDIM];
        #pragma unroll
        for (int j = 0; j < 4; j++) acc[j] += ol[r0 + j * 4][k] * wval;
    }
    #pragma unroll
    for (int j = 0; j < 4; j++)
        o[(size_t)(tb + r0 + j * 4) * HID + h * VDIM + v] = f2bf(acc[j]);
}

extern "C" void kernel_launch(void* const* d_in, const int* in_sizes, int n_in,
                              void* d_out, int out_size, void* d_ws, size_t ws_size,
                              hipStream_t stream) {
    const int*   positions = (const int*)d_in[0];
    const float* hs    = (const float*)d_in[1];
    const float* w_qa  = (const float*)d_in[2];
    const float* g_qa  = (const float*)d_in[3];
    const float* w_qb  = (const float*)d_in[4];
    const float* w_kva = (const float*)d_in[5];
    const float* g_kva = (const float*)d_in[6];
    const float* w_kc  = (const float*)d_in[7];
    const float* w_vc  = (const float*)d_in[8];
    const float* w_o   = (const float*)d_in[9];
    float* out = (float*)d_out;

    float* ws    = (float*)d_ws;
    float* qa    = ws;                               // T*768
    float* q     = qa    + (size_t)TT * QLORA;       // T*3840
    float* kin   = q     + (size_t)TT * NH * QHD;    // T*288
    float* o_lat = kin   + (size_t)TT * DQK;         // T*40*256
    ushort* ub     = (ushort*)(o_lat + (size_t)TT * NH * KVLORA);
    ushort* hs_bf  = ub;                             // T*2560
    ushort* qa_bf  = hs_bf  + (size_t)TT * HID;      // T*768
    ushort* o_bf   = qa_bf  + (size_t)TT * QLORA;    // T*2560
    ushort* kin_bf = o_bf   + (size_t)TT * HID;      // T*288
    ushort* qin_bf = kin_bf + (size_t)TT * DQK;      // T*40*288
    ushort* w_qa_t  = qin_bf + (size_t)TT * NH * DQK;       // 768*2560
    ushort* w_qb_t  = w_qa_t + (size_t)QLORA * HID;         // 3840*768
    ushort* w_kva_t = w_qb_t + (size_t)(NH * QHD) * QLORA;  // 288*2560
    ushort* w_o_t   = w_kva_t + (size_t)DQK * HID;          // 2560*2560

    // ---- casts / transposes (independent of each other) ----
    cast_bf16<<<(TT * HID) / 1024, 256, 0, stream>>>(hs, hs_bf, TT * HID);
    transpose_cast<<<dim3(QLORA / 32, HID / 32), 256, 0, stream>>>(w_qa, w_qa_t, HID, QLORA);
    transpose_cast<<<dim3((NH * QHD) / 32, QLORA / 32), 256, 0, stream>>>(w_qb, w_qb_t, QLORA, NH * QHD);
    transpose_cast<<<dim3(DQK / 32, HID / 32), 256, 0, stream>>>(w_kva, w_kva_t, HID, DQK);
    transpose_cast<<<dim3(HID / 32, HID / 32), 256, 0, stream>>>(w_o, w_o_t, HID, HID);

    // 1. qa = hs @ w_qa (MFMA, 128x64 tile: N=768 -> 192 blocks); RMS -> qa_bf
    gemm_bf16_n64<<<dim3(QLORA / 64, TT / 128), 256, 0, stream>>>(hs_bf, w_qa_t, qa, TT, QLORA, HID);
    rms_qa<<<TT, 256, 0, stream>>>(qa, g_qa, qa_bf);
    // 2. q = qa @ w_qb (MFMA)
    gemm_bf16<<<dim3((NH * QHD) / 128, TT / 128), 256, 0, stream>>>(qa_bf, w_qb_t, q, TT, NH * QHD, QLORA);
    // 3. kin = hs @ w_kva (MFMA, 128x64 tile: N=288 -> 80 blocks); RMS+RoPE -> kin_bf
    gemm_bf16_n64<<<dim3((DQK + 63) / 64, TT / 128), 256, 0, stream>>>(hs_bf, w_kva_t, kin, TT, DQK, HID);
    kin_post<<<TT, 256, 0, stream>>>(kin, g_kva, positions, kin_bf);
    // 4. qin_bf = [q_nope @ w_kc[h] | rope(q_pe)] * scale
    build_qin<<<dim3(TT / QTB, NH), 256, 0, stream>>>(q, w_kc, positions, qin_bf);
    // 5. flash MFMA attention (uniform-work pairing: 16 x 40 blocks, 68 iters each)
    flash_attn<<<dim3(TT / 128, NH), 256, 0, stream>>>(qin_bf, kin_bf, o_lat);
    // 6. o_bf = o_lat @ w_vc
    ogemm<<<dim3(TT / 16, NH), 256, 0, stream>>>(o_lat, w_vc, o_bf);
    // 7. out = o_bf @ w_o (MFMA)
    gemm_bf16<<<dim3(HID / 128, TT / 128), 256, 0, stream>>>(o_bf, w_o_t, out, TT, HID, HID);
}

// Round 8
// 839.199 us; speedup vs baseline: 1.4132x; 1.4132x over previous
//
#include <hip/hip_runtime.h>
#include <hip/hip_bf16.h>
#include <math.h>

#define TT 2048
#define HID 2560
#define NH 40
#define NOPE 64
#define ROPE 32
#define VDIM 64
#define QLORA 768
#define KVLORA 256
#define DQK 288            // KVLORA + ROPE
#define QHD 96             // NOPE + ROPE
#define EPS 1e-5f
#define THETA 10000.0f

typedef __attribute__((ext_vector_type(8))) short bf16x8;
typedef __attribute__((ext_vector_type(4))) float f32x4;
typedef __attribute__((address_space(1))) const void* gas_t;
typedef __attribute__((address_space(3))) void* las_t;

static __device__ __forceinline__ ushort f2bf(float x) {
    __hip_bfloat16 b = __float2bfloat16(x);
    return *reinterpret_cast<ushort*>(&b);
}

// ---------------- flat fp32 -> bf16 cast ----------------
__global__ __launch_bounds__(256) void cast_bf16(const float* __restrict__ x,
                                                 ushort* __restrict__ y, int n) {
    int i = (blockIdx.x * 256 + threadIdx.x) * 4;
    if (i + 3 < n) {
        float4 v = *(const float4*)(x + i);
        y[i]     = f2bf(v.x);
        y[i + 1] = f2bf(v.y);
        y[i + 2] = f2bf(v.z);
        y[i + 3] = f2bf(v.w);
    }
}

// ------------- transpose + cast: w (K x N fp32) -> wt (N x K bf16) -------------
__global__ __launch_bounds__(256) void transpose_cast(const float* __restrict__ w,
                                                      ushort* __restrict__ wt,
                                                      int K, int N) {
    __shared__ float tile[32][33];
    int bn = blockIdx.x * 32, bk = blockIdx.y * 32;
    int tx = threadIdx.x % 32, ty = threadIdx.x / 32;   // 32 x 8
    #pragma unroll
    for (int i = 0; i < 32; i += 8) {
        int k = bk + ty + i, n = bn + tx;
        if (k < K && n < N) tile[ty + i][tx] = w[(size_t)k * N + n];
    }
    __syncthreads();
    #pragma unroll
    for (int i = 0; i < 32; i += 8) {
        int n = bn + ty + i, k = bk + tx;
        if (n < N && k < K) wt[(size_t)n * K + k] = f2bf(tile[tx][ty + i]);
    }
}

// ------- bf16 MFMA GEMM (m97 structure): C(MxN,f32) = A(MxK,bf16) @ Bt(NxK,bf16)^T -------
__global__ __launch_bounds__(256, 2) void gemm_bf16(const ushort* __restrict__ A,
                                                    const ushort* __restrict__ Bt,
                                                    float* __restrict__ C,
                                                    int M, int N, int K) {
    __shared__ ushort As[128 * 32];
    __shared__ ushort Bs[128 * 32];
    const int tid  = threadIdx.x;
    const int lane = tid & 63;
    const int wv   = tid >> 6;
    const int col  = lane & 15;
    const int quad = lane >> 4;
    const int m0 = blockIdx.y * 128, n0 = blockIdx.x * 128;
    const int wr = (wv >> 1) * 64, wc = (wv & 1) * 64;

    f32x4 acc[4][4];
    #pragma unroll
    for (int i = 0; i < 4; i++)
        #pragma unroll
        for (int j = 0; j < 4; j++) acc[i][j] = (f32x4){0.f, 0.f, 0.f, 0.f};

    for (int k0 = 0; k0 < K; k0 += 32) {
        #pragma unroll
        for (int j = 0; j < 2; j++) {
            int slot = wv * 128 + j * 64 + lane;     // 0..511
            int row  = slot >> 2;
            int ch   = slot & 3;
            const ushort* ga = A + (size_t)(m0 + row) * K + k0 + ch * 8;
            __builtin_amdgcn_global_load_lds((gas_t)ga, (las_t)(As + slot * 8), 16, 0, 0);
            int brow = n0 + row; if (brow >= N) brow = N - 1;   // clamp (edge tiles)
            const ushort* gb = Bt + (size_t)brow * K + k0 + ch * 8;
            __builtin_amdgcn_global_load_lds((gas_t)gb, (las_t)(Bs + slot * 8), 16, 0, 0);
        }
        __syncthreads();
        bf16x8 af[4], bfr[4];
        #pragma unroll
        for (int i = 0; i < 4; i++)
            af[i] = *(const bf16x8*)(As + (wr + i * 16 + col) * 32 + quad * 8);
        #pragma unroll
        for (int j = 0; j < 4; j++)
            bfr[j] = *(const bf16x8*)(Bs + (wc + j * 16 + col) * 32 + quad * 8);
        #pragma unroll
        for (int i = 0; i < 4; i++)
            #pragma unroll
            for (int j = 0; j < 4; j++)
                acc[i][j] = __builtin_amdgcn_mfma_f32_16x16x32_bf16(af[i], bfr[j], acc[i][j], 0, 0, 0);
        __syncthreads();
    }
    #pragma unroll
    for (int i = 0; i < 4; i++) {
        int gr = m0 + wr + i * 16 + quad * 4;
        #pragma unroll
        for (int j = 0; j < 4; j++) {
            int gc = n0 + wc + j * 16 + col;
            if (gc < N) {
                #pragma unroll
                for (int r = 0; r < 4; r++)
                    C[(size_t)(gr + r) * N + gc] = acc[i][j][r];
            }
        }
    }
}

// ------- 128x64-tile variant for narrow-N GEMMs (N=768, N=288): better grid occupancy -------
__global__ __launch_bounds__(256, 4) void gemm_bf16_n64(const ushort* __restrict__ A,
                                                        const ushort* __restrict__ Bt,
                                                        float* __restrict__ C,
                                                        int M, int N, int K) {
    __shared__ ushort As[128 * 32];
    __shared__ ushort Bs[64 * 32];
    const int tid  = threadIdx.x;
    const int lane = tid & 63;
    const int wv   = tid >> 6;
    const int col  = lane & 15;
    const int quad = lane >> 4;
    const int m0 = blockIdx.y * 128, n0 = blockIdx.x * 64;
    const int wr = wv * 32;

    f32x4 acc[2][4];
    #pragma unroll
    for (int i = 0; i < 2; i++)
        #pragma unroll
        for (int j = 0; j < 4; j++) acc[i][j] = (f32x4){0.f, 0.f, 0.f, 0.f};

    for (int k0 = 0; k0 < K; k0 += 32) {
        #pragma unroll
        for (int j = 0; j < 2; j++) {                // A: 512 slots, 2/thread
            int slot = j * 256 + tid;
            int row  = slot >> 2;
            int ch   = slot & 3;
            const ushort* ga = A + (size_t)(m0 + row) * K + k0 + ch * 8;
            __builtin_amdgcn_global_load_lds((gas_t)ga, (las_t)(As + slot * 8), 16, 0, 0);
        }
        {                                            // B: 256 slots, 1/thread
            int row = tid >> 2;
            int ch  = tid & 3;
            int brow = n0 + row; if (brow >= N) brow = N - 1;
            const ushort* gb = Bt + (size_t)brow * K + k0 + ch * 8;
            __builtin_amdgcn_global_load_lds((gas_t)gb, (las_t)(Bs + tid * 8), 16, 0, 0);
        }
        __syncthreads();
        bf16x8 af[2], bfr[4];
        #pragma unroll
        for (int i = 0; i < 2; i++)
            af[i] = *(const bf16x8*)(As + (wr + i * 16 + col) * 32 + quad * 8);
        #pragma unroll
        for (int j = 0; j < 4; j++)
            bfr[j] = *(const bf16x8*)(Bs + (j * 16 + col) * 32 + quad * 8);
        #pragma unroll
        for (int i = 0; i < 2; i++)
            #pragma unroll
            for (int j = 0; j < 4; j++)
                acc[i][j] = __builtin_amdgcn_mfma_f32_16x16x32_bf16(af[i], bfr[j], acc[i][j], 0, 0, 0);
        __syncthreads();
    }
    #pragma unroll
    for (int i = 0; i < 2; i++) {
        int gr = m0 + wr + i * 16 + quad * 4;
        #pragma unroll
        for (int j = 0; j < 4; j++) {
            int gc = n0 + j * 16 + col;
            if (gc < N) {
                #pragma unroll
                for (int r = 0; r < 4; r++)
                    C[(size_t)(gr + r) * N + gc] = acc[i][j][r];
            }
        }
    }
}

// ---------------- RMS norm: fp32 in, bf16 out ----------------
__global__ __launch_bounds__(256) void rms_qa(const float* __restrict__ x,
                                              const float* __restrict__ g,
                                              ushort* __restrict__ y) {
    int t = blockIdx.x, tid = threadIdx.x;
    __shared__ float red[256];
    __shared__ float s_inv;
    const float* row = x + (size_t)t * QLORA;
    float ss = 0.f;
    for (int i = tid; i < QLORA; i += 256) { float v = row[i]; ss += v * v; }
    red[tid] = ss; __syncthreads();
    for (int s = 128; s > 0; s >>= 1) { if (tid < s) red[tid] += red[tid + s]; __syncthreads(); }
    if (tid == 0) s_inv = rsqrtf(red[0] / (float)QLORA + EPS);
    __syncthreads();
    float si = s_inv;
    ushort* orow = y + (size_t)t * QLORA;
    for (int i = tid; i < QLORA; i += 256) orow[i] = f2bf(row[i] * si * g[i]);
}

// ------- latent post: RMS first 256, RoPE last 32 -> bf16 kin_bf (T x 288) -------
__global__ __launch_bounds__(256) void kin_post(const float* __restrict__ kin,
                                                const float* __restrict__ g,
                                                const int* __restrict__ positions,
                                                ushort* __restrict__ kin_bf) {
    int t = blockIdx.x, tid = threadIdx.x;
    __shared__ float red[256];
    __shared__ float s_inv;
    const float* row = kin + (size_t)t * DQK;
    float v = row[tid];
    red[tid] = v * v; __syncthreads();
    for (int s = 128; s > 0; s >>= 1) { if (tid < s) red[tid] += red[tid + s]; __syncthreads(); }
    if (tid == 0) s_inv = rsqrtf(red[0] / (float)KVLORA + EPS);
    __syncthreads();
    ushort* orow = kin_bf + (size_t)t * DQK;
    orow[tid] = f2bf(v * s_inv * g[tid]);
    if (tid < 16) {
        float pos = (float)positions[t];
        float freq = powf(THETA, -(float)tid / 16.0f);
        float f = pos * freq;
        float c = cosf(f), s = sinf(f);
        float x1 = row[KVLORA + tid], x2 = row[KVLORA + 16 + tid];
        orow[KVLORA + tid]      = f2bf(x1 * c - x2 * s);
        orow[KVLORA + 16 + tid] = f2bf(x2 * c + x1 * s);
    }
}

// --- q_in build (tiled: 16 t-rows per block, w_kc[h] read once per block) ---
#define QTB 16
__global__ __launch_bounds__(256) void build_qin(const float* __restrict__ q,
                                                 const float* __restrict__ w_kc,
                                                 const int* __restrict__ positions,
                                                 ushort* __restrict__ qin) {
    int tb = blockIdx.x * QTB, h = blockIdx.y, tid = threadIdx.x;
    const float scale = 0.10206207261596577f;   // 1/sqrt(96), folded into Q
    __shared__ float qn[QTB][NOPE];
    __shared__ float qp[QTB][ROPE];
    // load 16 q rows (96 floats each)
    for (int i = tid; i < QTB * QHD; i += 256) {
        int r = i / QHD, cidx = i % QHD;
        float v = q[(size_t)(tb + r) * (NH * QHD) + h * QHD + cidx];
        if (cidx < NOPE) qn[r][cidx] = v;
        else             qp[r][cidx - NOPE] = v;
    }
    __syncthreads();
    // each thread owns one latent dim k for all 16 rows
    int k = tid;
    float acc[QTB];
    #pragma unroll
    for (int r = 0; r < QTB; r++) acc[r] = 0.f;
    const float* w = w_kc + (size_t)h * NOPE * KVLORA + k;
    for (int n = 0; n < NOPE; n++) {
        float wval = w[(size_t)n * KVLORA];
        #pragma unroll
        for (int r = 0; r < QTB; r++) acc[r] += qn[r][n] * wval;
    }
    #pragma unroll
    for (int r = 0; r < QTB; r++)
        qin[((size_t)(tb + r) * NH + h) * DQK + k] = f2bf(acc[r] * scale);
    // rope: 16 rows x 16 freqs = 256 threads
    int r = tid >> 4, fi = tid & 15;
    float pos = (float)positions[tb + r];
    float freq = powf(THETA, -(float)fi / 16.0f);
    float f = pos * freq;
    float c = cosf(f), s = sinf(f);
    float x1 = qp[r][fi], x2 = qp[r][16 + fi];
    ushort* orow = qin + ((size_t)(tb + r) * NH + h) * DQK;
    orow[KVLORA + fi]      = f2bf((x1 * c - x2 * s) * scale);
    orow[KVLORA + 16 + fi] = f2bf((x2 * c + x1 * s) * scale);
}

// ---------------- flash MFMA attention (r0 structure, best measured: 405 us) ----------------
#define KSTR 296
#define VSTR 72
#define PSTR 72

__global__ __launch_bounds__(256, 2) void flash_attn(const ushort* __restrict__ qin,
                                                     const ushort* __restrict__ kin,
                                                     float* __restrict__ o_lat) {
    __shared__ ushort lds[64 * KSTR + 256 * VSTR];
    ushort* krow = lds;
    ushort* vt   = lds + 64 * KSTR;
    ushort* pbuf = lds;                 // alias of krow region

    const int tid  = threadIdx.x;
    const int lane = tid & 63;
    const int wv   = tid >> 6;
    const int col  = lane & 15;
    const int quad = lane >> 4;
    const int h    = blockIdx.y;
    const int qb   = ((int)gridDim.x - 1 - (int)blockIdx.x) * 64;

    bf16x8 qf[9];
    {
        const ushort* base = qin + ((size_t)(qb + wv * 16 + col) * NH + h) * DQK + quad * 8;
        #pragma unroll
        for (int k = 0; k < 9; k++) qf[k] = *(const bf16x8*)(base + k * 32);
    }

    f32x4 of[16];
    #pragma unroll
    for (int i = 0; i < 16; i++) of[i] = (f32x4){0.f, 0.f, 0.f, 0.f};
    float m_i[4] = {-1e30f, -1e30f, -1e30f, -1e30f};
    float l_i[4] = {0.f, 0.f, 0.f, 0.f};

    for (int s0 = 0; s0 <= qb; s0 += 64) {
        __syncthreads();
        {
            const ushort* src = kin + (size_t)(s0 + lane) * DQK;
            #pragma unroll
            for (int ci = 0; ci < 9; ci++) {
                int c = ci * 4 + wv;
                uint4 u = *(const uint4*)(src + c * 8);
                *(uint4*)(krow + lane * KSTR + c * 8) = u;
                if (c < 32) {
                    const ushort* up = (const ushort*)&u;
                    #pragma unroll
                    for (int j = 0; j < 8; j++)
                        vt[(c * 8 + j) * VSTR + lane] = up[j];
                }
            }
        }
        __syncthreads();
        f32x4 sf[4];
        #pragma unroll
        for (int tc = 0; tc < 4; tc++) sf[tc] = (f32x4){0.f, 0.f, 0.f, 0.f};
        #pragma unroll
        for (int k = 0; k < 9; k++) {
            #pragma unroll
            for (int tc = 0; tc < 4; tc++) {
                bf16x8 bf = *(const bf16x8*)(krow + (tc * 16 + col) * KSTR + k * 32 + quad * 8);
                sf[tc] = __builtin_amdgcn_mfma_f32_16x16x32_bf16(qf[k], bf, sf[tc], 0, 0, 0);
            }
        }
        if (s0 == qb) {
            #pragma unroll
            for (int tc = 0; tc < 4; tc++)
                #pragma unroll
                for (int r = 0; r < 4; r++)
                    if (tc * 16 + col > wv * 16 + quad * 4 + r) sf[tc][r] = -1e30f;
        }
        float mnew[4], alpha[4];
        #pragma unroll
        for (int r = 0; r < 4; r++) {
            float mx = fmaxf(fmaxf(sf[0][r], sf[1][r]), fmaxf(sf[2][r], sf[3][r]));
            mx = fmaxf(mx, __shfl_xor(mx, 1));
            mx = fmaxf(mx, __shfl_xor(mx, 2));
            mx = fmaxf(mx, __shfl_xor(mx, 4));
            mx = fmaxf(mx, __shfl_xor(mx, 8));
            mnew[r] = fmaxf(m_i[r], mx);
            alpha[r] = __expf(m_i[r] - mnew[r]);
            m_i[r] = mnew[r];
        }
        float rsum[4];
        #pragma unroll
        for (int r = 0; r < 4; r++) {
            float s = 0.f;
            #pragma unroll
            for (int tc = 0; tc < 4; tc++) {
                float p = __expf(sf[tc][r] - mnew[r]);
                sf[tc][r] = p;
                s += p;
            }
            s += __shfl_xor(s, 1);
            s += __shfl_xor(s, 2);
            s += __shfl_xor(s, 4);
            s += __shfl_xor(s, 8);
            rsum[r] = s;
        }
        #pragma unroll
        for (int r = 0; r < 4; r++) l_i[r] = l_i[r] * alpha[r] + rsum[r];
        #pragma unroll
        for (int i = 0; i < 16; i++)
            #pragma unroll
            for (int r = 0; r < 4; r++) of[i][r] *= alpha[r];
        __syncthreads();
        #pragma unroll
        for (int tc = 0; tc < 4; tc++)
            #pragma unroll
            for (int r = 0; r < 4; r++)
                pbuf[(wv * 16 + quad * 4 + r) * PSTR + tc * 16 + col] = f2bf(sf[tc][r]);
        __syncthreads();
        bf16x8 pa[2];
        #pragma unroll
        for (int ks = 0; ks < 2; ks++)
            pa[ks] = *(const bf16x8*)(pbuf + (wv * 16 + col) * PSTR + ks * 32 + quad * 8);
        #pragma unroll
        for (int nt = 0; nt < 16; nt++) {
            #pragma unroll
            for (int ks = 0; ks < 2; ks++) {
                bf16x8 vb = *(const bf16x8*)(vt + (nt * 16 + col) * VSTR + ks * 32 + quad * 8);
                of[nt] = __builtin_amdgcn_mfma_f32_16x16x32_bf16(pa[ks], vb, of[nt], 0, 0, 0);
            }
        }
    }
    #pragma unroll
    for (int r = 0; r < 4; r++) {
        float inv = 1.0f / l_i[r];
        int row = qb + wv * 16 + quad * 4 + r;
        float* dst = o_lat + ((size_t)row * NH + h) * KVLORA + col;
        #pragma unroll
        for (int nt = 0; nt < 16; nt++) dst[nt * 16] = of[nt][r] * inv;
    }
}

// ------- o_bf = o_lat @ w_vc[h] (tiled: 16 t-rows per block, w_vc[h] read once) -------
__global__ __launch_bounds__(256) void ogemm(const float* __restrict__ o_lat,
                                             const float* __restrict__ w_vc,
                                             ushort* __restrict__ o) {
    int tb = blockIdx.x * 16, h = blockIdx.y, tid = threadIdx.x;
    __shared__ float ol[16][KVLORA];
    for (int i = tid; i < 16 * KVLORA; i += 256) {
        int r = i >> 8, k = i & 255;
        ol[r][k] = o_lat[((size_t)(tb + r) * NH + h) * KVLORA + k];
    }
    __syncthreads();
    int v = tid & 63, r0 = tid >> 6;       // 4 rows/thread: r0, r0+4, r0+8, r0+12
    float acc[4] = {0.f, 0.f, 0.f, 0.f};
    const float* w = w_vc + (size_t)h * KVLORA * VDIM + v;
    for (int k = 0; k < KVLORA; k++) {
        float wval = w[(size_t)k * VDIM];
        #pragma unroll
        for (int j = 0; j < 4; j++) acc[j] += ol[r0 + j * 4][k] * wval;
    }
    #pragma unroll
    for (int j = 0; j < 4; j++)
        o[(size_t)(tb + r0 + j * 4) * HID + h * VDIM + v] = f2bf(acc[j]);
}

extern "C" void kernel_launch(void* const* d_in, const int* in_sizes, int n_in,
                              void* d_out, int out_size, void* d_ws, size_t ws_size,
                              hipStream_t stream) {
    const int*   positions = (const int*)d_in[0];
    const float* hs    = (const float*)d_in[1];
    const float* w_qa  = (const float*)d_in[2];
    const float* g_qa  = (const float*)d_in[3];
    const float* w_qb  = (const float*)d_in[4];
    const float* w_kva = (const float*)d_in[5];
    const float* g_kva = (const float*)d_in[6];
    const float* w_kc  = (const float*)d_in[7];
    const float* w_vc  = (const float*)d_in[8];
    const float* w_o   = (const float*)d_in[9];
    float* out = (float*)d_out;

    float* ws    = (float*)d_ws;
    float* qa    = ws;                               // T*768
    float* q     = qa    + (size_t)TT * QLORA;       // T*3840
    float* kin   = q     + (size_t)TT * NH * QHD;    // T*288
    float* o_lat = kin   + (size_t)TT * DQK;         // T*40*256
    ushort* ub     = (ushort*)(o_lat + (size_t)TT * NH * KVLORA);
    ushort* hs_bf  = ub;                             // T*2560
    ushort* qa_bf  = hs_bf  + (size_t)TT * HID;      // T*768
    ushort* o_bf   = qa_bf  + (size_t)TT * QLORA;    // T*2560
    ushort* kin_bf = o_bf   + (size_t)TT * HID;      // T*288
    ushort* qin_bf = kin_bf + (size_t)TT * DQK;      // T*40*288
    ushort* w_qa_t  = qin_bf + (size_t)TT * NH * DQK;       // 768*2560
    ushort* w_qb_t  = w_qa_t + (size_t)QLORA * HID;         // 3840*768
    ushort* w_kva_t = w_qb_t + (size_t)(NH * QHD) * QLORA;  // 288*2560
    ushort* w_o_t   = w_kva_t + (size_t)DQK * HID;          // 2560*2560

    // ---- casts / transposes (independent of each other) ----
    cast_bf16<<<(TT * HID) / 1024, 256, 0, stream>>>(hs, hs_bf, TT * HID);
    transpose_cast<<<dim3(QLORA / 32, HID / 32), 256, 0, stream>>>(w_qa, w_qa_t, HID, QLORA);
    transpose_cast<<<dim3((NH * QHD) / 32, QLORA / 32), 256, 0, stream>>>(w_qb, w_qb_t, QLORA, NH * QHD);
    transpose_cast<<<dim3(DQK / 32, HID / 32), 256, 0, stream>>>(w_kva, w_kva_t, HID, DQK);
    transpose_cast<<<dim3(HID / 32, HID / 32), 256, 0, stream>>>(w_o, w_o_t, HID, HID);

    // 1. qa = hs @ w_qa (MFMA, 128x64 tile: N=768 -> 192 blocks); RMS -> qa_bf
    gemm_bf16_n64<<<dim3(QLORA / 64, TT / 128), 256, 0, stream>>>(hs_bf, w_qa_t, qa, TT, QLORA, HID);
    rms_qa<<<TT, 256, 0, stream>>>(qa, g_qa, qa_bf);
    // 2. q = qa @ w_qb (MFMA)
    gemm_bf16<<<dim3((NH * QHD) / 128, TT / 128), 256, 0, stream>>>(qa_bf, w_qb_t, q, TT, NH * QHD, QLORA);
    // 3. kin = hs @ w_kva (MFMA, 128x64 tile: N=288 -> 80 blocks); RMS+RoPE -> kin_bf
    gemm_bf16_n64<<<dim3((DQK + 63) / 64, TT / 128), 256, 0, stream>>>(hs_bf, w_kva_t, kin, TT, DQK, HID);
    kin_post<<<TT, 256, 0, stream>>>(kin, g_kva, positions, kin_bf);
    // 4. qin_bf = [q_nope @ w_kc[h] | rope(q_pe)] * scale
    build_qin<<<dim3(TT / QTB, NH), 256, 0, stream>>>(q, w_kc, positions, qin_bf);
    // 5. flash MFMA attention (r0 structure)
    flash_attn<<<dim3(TT / 64, NH), 256, 0, stream>>>(qin_bf, kin_bf, o_lat);
    // 6. o_bf = o_lat @ w_vc
    ogemm<<<dim3(TT / 16, NH), 256, 0, stream>>>(o_lat, w_vc, o_bf);
    // 7. out = o_bf @ w_o (MFMA)
    gemm_bf16<<<dim3(HID / 128, TT / 128), 256, 0, stream>>>(o_bf, w_o_t, out, TT, HID, HID);
}

// Round 10
// 778.808 us; speedup vs baseline: 1.5228x; 1.0775x over previous
//
#include <hip/hip_runtime.h>
#include <hip/hip_bf16.h>
#include <math.h>

#define TT 2048
#define HID 2560
#define NH 40
#define NOPE 64
#define ROPE 32
#define VDIM 64
#define QLORA 768
#define KVLORA 256
#define DQK 288            // KVLORA + ROPE
#define QHD 96             // NOPE + ROPE
#define EPS 1e-5f
#define THETA 10000.0f

typedef __attribute__((ext_vector_type(8))) short bf16x8;
typedef __attribute__((ext_vector_type(4))) float f32x4;
typedef __attribute__((address_space(1))) const void* gas_t;
typedef __attribute__((address_space(3))) void* las_t;

static __device__ __forceinline__ ushort f2bf(float x) {
    __hip_bfloat16 b = __float2bfloat16(x);
    return *reinterpret_cast<ushort*>(&b);
}

// ---------------- flat fp32 -> bf16 cast ----------------
__global__ __launch_bounds__(256) void cast_bf16(const float* __restrict__ x,
                                                 ushort* __restrict__ y, int n) {
    int i = (blockIdx.x * 256 + threadIdx.x) * 4;
    if (i + 3 < n) {
        float4 v = *(const float4*)(x + i);
        y[i]     = f2bf(v.x);
        y[i + 1] = f2bf(v.y);
        y[i + 2] = f2bf(v.z);
        y[i + 3] = f2bf(v.w);
    }
}

// ------------- transpose + cast: w (K x N fp32) -> wt (N x K bf16) -------------
__global__ __launch_bounds__(256) void transpose_cast(const float* __restrict__ w,
                                                      ushort* __restrict__ wt,
                                                      int K, int N) {
    __shared__ float tile[32][33];
    int bn = blockIdx.x * 32, bk = blockIdx.y * 32;
    int tx = threadIdx.x % 32, ty = threadIdx.x / 32;   // 32 x 8
    #pragma unroll
    for (int i = 0; i < 32; i += 8) {
        int k = bk + ty + i, n = bn + tx;
        if (k < K && n < N) tile[ty + i][tx] = w[(size_t)k * N + n];
    }
    __syncthreads();
    #pragma unroll
    for (int i = 0; i < 32; i += 8) {
        int n = bn + ty + i, k = bk + tx;
        if (n < N && k < K) wt[(size_t)n * K + k] = f2bf(tile[tx][ty + i]);
    }
}

// ---- per-head transpose: w_vc (H, K=256, V=64) fp32 -> w_vct (H, V=64, K=256) bf16 ----
__global__ __launch_bounds__(256) void transpose_vc(const float* __restrict__ w,
                                                    ushort* __restrict__ wt) {
    __shared__ float tile[32][33];
    int h = blockIdx.z;
    const float* src = w + (size_t)h * KVLORA * VDIM;
    ushort* dst = wt + (size_t)h * VDIM * KVLORA;
    int bn = blockIdx.x * 32, bk = blockIdx.y * 32;     // n over V, k over KVLORA
    int tx = threadIdx.x % 32, ty = threadIdx.x / 32;
    #pragma unroll
    for (int i = 0; i < 32; i += 8)
        tile[ty + i][tx] = src[(size_t)(bk + ty + i) * VDIM + bn + tx];
    __syncthreads();
    #pragma unroll
    for (int i = 0; i < 32; i += 8)
        dst[(size_t)(bn + ty + i) * KVLORA + bk + tx] = f2bf(tile[tx][ty + i]);
}

// ------- bf16 MFMA GEMM (m97 structure): C(MxN,f32) = A(MxK,bf16) @ Bt(NxK,bf16)^T -------
__global__ __launch_bounds__(256, 2) void gemm_bf16(const ushort* __restrict__ A,
                                                    const ushort* __restrict__ Bt,
                                                    float* __restrict__ C,
                                                    int M, int N, int K) {
    __shared__ ushort As[128 * 32];
    __shared__ ushort Bs[128 * 32];
    const int tid  = threadIdx.x;
    const int lane = tid & 63;
    const int wv   = tid >> 6;
    const int col  = lane & 15;
    const int quad = lane >> 4;
    const int m0 = blockIdx.y * 128, n0 = blockIdx.x * 128;
    const int wr = (wv >> 1) * 64, wc = (wv & 1) * 64;

    f32x4 acc[4][4];
    #pragma unroll
    for (int i = 0; i < 4; i++)
        #pragma unroll
        for (int j = 0; j < 4; j++) acc[i][j] = (f32x4){0.f, 0.f, 0.f, 0.f};

    for (int k0 = 0; k0 < K; k0 += 32) {
        #pragma unroll
        for (int j = 0; j < 2; j++) {
            int slot = wv * 128 + j * 64 + lane;     // 0..511
            int row  = slot >> 2;
            int ch   = slot & 3;
            const ushort* ga = A + (size_t)(m0 + row) * K + k0 + ch * 8;
            __builtin_amdgcn_global_load_lds((gas_t)ga, (las_t)(As + slot * 8), 16, 0, 0);
            int brow = n0 + row; if (brow >= N) brow = N - 1;   // clamp (edge tiles)
            const ushort* gb = Bt + (size_t)brow * K + k0 + ch * 8;
            __builtin_amdgcn_global_load_lds((gas_t)gb, (las_t)(Bs + slot * 8), 16, 0, 0);
        }
        __syncthreads();
        bf16x8 af[4], bfr[4];
        #pragma unroll
        for (int i = 0; i < 4; i++)
            af[i] = *(const bf16x8*)(As + (wr + i * 16 + col) * 32 + quad * 8);
        #pragma unroll
        for (int j = 0; j < 4; j++)
            bfr[j] = *(const bf16x8*)(Bs + (wc + j * 16 + col) * 32 + quad * 8);
        #pragma unroll
        for (int i = 0; i < 4; i++)
            #pragma unroll
            for (int j = 0; j < 4; j++)
                acc[i][j] = __builtin_amdgcn_mfma_f32_16x16x32_bf16(af[i], bfr[j], acc[i][j], 0, 0, 0);
        __syncthreads();
    }
    #pragma unroll
    for (int i = 0; i < 4; i++) {
        int gr = m0 + wr + i * 16 + quad * 4;
        #pragma unroll
        for (int j = 0; j < 4; j++) {
            int gc = n0 + wc + j * 16 + col;
            if (gc < N) {
                #pragma unroll
                for (int r = 0; r < 4; r++)
                    C[(size_t)(gr + r) * N + gc] = acc[i][j][r];
            }
        }
    }
}

// ------- 128x64-tile variant for narrow-N GEMMs (N=768, N=288): better grid occupancy -------
__global__ __launch_bounds__(256, 4) void gemm_bf16_n64(const ushort* __restrict__ A,
                                                        const ushort* __restrict__ Bt,
                                                        float* __restrict__ C,
                                                        int M, int N, int K) {
    __shared__ ushort As[128 * 32];
    __shared__ ushort Bs[64 * 32];
    const int tid  = threadIdx.x;
    const int lane = tid & 63;
    const int wv   = tid >> 6;
    const int col  = lane & 15;
    const int quad = lane >> 4;
    const int m0 = blockIdx.y * 128, n0 = blockIdx.x * 64;
    const int wr = wv * 32;

    f32x4 acc[2][4];
    #pragma unroll
    for (int i = 0; i < 2; i++)
        #pragma unroll
        for (int j = 0; j < 4; j++) acc[i][j] = (f32x4){0.f, 0.f, 0.f, 0.f};

    for (int k0 = 0; k0 < K; k0 += 32) {
        #pragma unroll
        for (int j = 0; j < 2; j++) {                // A: 512 slots, 2/thread
            int slot = j * 256 + tid;
            int row  = slot >> 2;
            int ch   = slot & 3;
            const ushort* ga = A + (size_t)(m0 + row) * K + k0 + ch * 8;
            __builtin_amdgcn_global_load_lds((gas_t)ga, (las_t)(As + slot * 8), 16, 0, 0);
        }
        {                                            // B: 256 slots, 1/thread
            int row = tid >> 2;
            int ch  = tid & 3;
            int brow = n0 + row; if (brow >= N) brow = N - 1;
            const ushort* gb = Bt + (size_t)brow * K + k0 + ch * 8;
            __builtin_amdgcn_global_load_lds((gas_t)gb, (las_t)(Bs + tid * 8), 16, 0, 0);
        }
        __syncthreads();
        bf16x8 af[2], bfr[4];
        #pragma unroll
        for (int i = 0; i < 2; i++)
            af[i] = *(const bf16x8*)(As + (wr + i * 16 + col) * 32 + quad * 8);
        #pragma unroll
        for (int j = 0; j < 4; j++)
            bfr[j] = *(const bf16x8*)(Bs + (j * 16 + col) * 32 + quad * 8);
        #pragma unroll
        for (int i = 0; i < 2; i++)
            #pragma unroll
            for (int j = 0; j < 4; j++)
                acc[i][j] = __builtin_amdgcn_mfma_f32_16x16x32_bf16(af[i], bfr[j], acc[i][j], 0, 0, 0);
        __syncthreads();
    }
    #pragma unroll
    for (int i = 0; i < 2; i++) {
        int gr = m0 + wr + i * 16 + quad * 4;
        #pragma unroll
        for (int j = 0; j < 4; j++) {
            int gc = n0 + j * 16 + col;
            if (gc < N) {
                #pragma unroll
                for (int r = 0; r < 4; r++)
                    C[(size_t)(gr + r) * N + gc] = acc[i][j][r];
            }
        }
    }
}

// ---------------- RMS norm: fp32 in, bf16 out ----------------
__global__ __launch_bounds__(256) void rms_qa(const float* __restrict__ x,
                                              const float* __restrict__ g,
                                              ushort* __restrict__ y) {
    int t = blockIdx.x, tid = threadIdx.x;
    __shared__ float red[256];
    __shared__ float s_inv;
    const float* row = x + (size_t)t * QLORA;
    float ss = 0.f;
    for (int i = tid; i < QLORA; i += 256) { float v = row[i]; ss += v * v; }
    red[tid] = ss; __syncthreads();
    for (int s = 128; s > 0; s >>= 1) { if (tid < s) red[tid] += red[tid + s]; __syncthreads(); }
    if (tid == 0) s_inv = rsqrtf(red[0] / (float)QLORA + EPS);
    __syncthreads();
    float si = s_inv;
    ushort* orow = y + (size_t)t * QLORA;
    for (int i = tid; i < QLORA; i += 256) orow[i] = f2bf(row[i] * si * g[i]);
}

// ------- latent post: RMS first 256, RoPE last 32 -> bf16 kin_bf (T x 288) -------
__global__ __launch_bounds__(256) void kin_post(const float* __restrict__ kin,
                                                const float* __restrict__ g,
                                                const int* __restrict__ positions,
                                                ushort* __restrict__ kin_bf) {
    int t = blockIdx.x, tid = threadIdx.x;
    __shared__ float red[256];
    __shared__ float s_inv;
    const float* row = kin + (size_t)t * DQK;
    float v = row[tid];
    red[tid] = v * v; __syncthreads();
    for (int s = 128; s > 0; s >>= 1) { if (tid < s) red[tid] += red[tid + s]; __syncthreads(); }
    if (tid == 0) s_inv = rsqrtf(red[0] / (float)KVLORA + EPS);
    __syncthreads();
    ushort* orow = kin_bf + (size_t)t * DQK;
    orow[tid] = f2bf(v * s_inv * g[tid]);
    if (tid < 16) {
        float pos = (float)positions[t];
        float freq = powf(THETA, -(float)tid / 16.0f);
        float f = pos * freq;
        float c = cosf(f), s = sinf(f);
        float x1 = row[KVLORA + tid], x2 = row[KVLORA + 16 + tid];
        orow[KVLORA + tid]      = f2bf(x1 * c - x2 * s);
        orow[KVLORA + 16 + tid] = f2bf(x2 * c + x1 * s);
    }
}

// --- q_in build (tiled: 16 t-rows per block, w_kc[h] read once per block) ---
#define QTB 16
__global__ __launch_bounds__(256) void build_qin(const float* __restrict__ q,
                                                 const float* __restrict__ w_kc,
                                                 const int* __restrict__ positions,
                                                 ushort* __restrict__ qin) {
    int tb = blockIdx.x * QTB, h = blockIdx.y, tid = threadIdx.x;
    const float scale = 0.10206207261596577f;   // 1/sqrt(96), folded into Q
    __shared__ float qn[QTB][NOPE];
    __shared__ float qp[QTB][ROPE];
    // load 16 q rows (96 floats each)
    for (int i = tid; i < QTB * QHD; i += 256) {
        int r = i / QHD, cidx = i % QHD;
        float v = q[(size_t)(tb + r) * (NH * QHD) + h * QHD + cidx];
        if (cidx < NOPE) qn[r][cidx] = v;
        else             qp[r][cidx - NOPE] = v;
    }
    __syncthreads();
    // each thread owns one latent dim k for all 16 rows
    int k = tid;
    float acc[QTB];
    #pragma unroll
    for (int r = 0; r < QTB; r++) acc[r] = 0.f;
    const float* w = w_kc + (size_t)h * NOPE * KVLORA + k;
    for (int n = 0; n < NOPE; n++) {
        float wval = w[(size_t)n * KVLORA];
        #pragma unroll
        for (int r = 0; r < QTB; r++) acc[r] += qn[r][n] * wval;
    }
    #pragma unroll
    for (int r = 0; r < QTB; r++)
        qin[((size_t)(tb + r) * NH + h) * DQK + k] = f2bf(acc[r] * scale);
    // rope: 16 rows x 16 freqs = 256 threads
    int r = tid >> 4, fi = tid & 15;
    float pos = (float)positions[tb + r];
    float freq = powf(THETA, -(float)fi / 16.0f);
    float f = pos * freq;
    float c = cosf(f), s = sinf(f);
    float x1 = qp[r][fi], x2 = qp[r][16 + fi];
    ushort* orow = qin + ((size_t)(tb + r) * NH + h) * DQK;
    orow[KVLORA + fi]      = f2bf((x1 * c - x2 * s) * scale);
    orow[KVLORA + 16 + fi] = f2bf((x2 * c + x1 * s) * scale);
}

// ---------------- flash MFMA attention (r0 structure) + fused w_vc projection ----------------
// Epilogue reuses the dead K/V LDS regions: normalized O (bf16) -> krow region,
// w_vct[h] (64 x 256 bf16, L2-resident) -> vt region, then 32 MFMAs/wave project
// 256 latent dims -> 64 v dims and store bf16 directly into o_bf (T x HID).
// Removes the o_lat tensor (84 MB write + 84 MB read) and the ogemm kernel.
#define KSTR 296
#define VSTR 72
#define PSTR 72
#define OSTR 264

__global__ __launch_bounds__(256, 2) void flash_attn(const ushort* __restrict__ qin,
                                                     const ushort* __restrict__ kin,
                                                     const ushort* __restrict__ w_vct,
                                                     ushort* __restrict__ o_bf) {
    __shared__ __align__(16) ushort lds[64 * KSTR + 256 * VSTR];
    ushort* krow = lds;
    ushort* vt   = lds + 64 * KSTR;
    ushort* pbuf = lds;                 // alias of krow region

    const int tid  = threadIdx.x;
    const int lane = tid & 63;
    const int wv   = tid >> 6;
    const int col  = lane & 15;
    const int quad = lane >> 4;
    const int h    = blockIdx.y;
    const int qb   = ((int)gridDim.x - 1 - (int)blockIdx.x) * 64;

    bf16x8 qf[9];
    {
        const ushort* base = qin + ((size_t)(qb + wv * 16 + col) * NH + h) * DQK + quad * 8;
        #pragma unroll
        for (int k = 0; k < 9; k++) qf[k] = *(const bf16x8*)(base + k * 32);
    }

    f32x4 of[16];
    #pragma unroll
    for (int i = 0; i < 16; i++) of[i] = (f32x4){0.f, 0.f, 0.f, 0.f};
    float m_i[4] = {-1e30f, -1e30f, -1e30f, -1e30f};
    float l_i[4] = {0.f, 0.f, 0.f, 0.f};

    for (int s0 = 0; s0 <= qb; s0 += 64) {
        __syncthreads();
        {
            const ushort* src = kin + (size_t)(s0 + lane) * DQK;
            #pragma unroll
            for (int ci = 0; ci < 9; ci++) {
                int c = ci * 4 + wv;
                uint4 u = *(const uint4*)(src + c * 8);
                *(uint4*)(krow + lane * KSTR + c * 8) = u;
                if (c < 32) {
                    const ushort* up = (const ushort*)&u;
                    #pragma unroll
                    for (int j = 0; j < 8; j++)
                        vt[(c * 8 + j) * VSTR + lane] = up[j];
                }
            }
        }
        __syncthreads();
        f32x4 sf[4];
        #pragma unroll
        for (int tc = 0; tc < 4; tc++) sf[tc] = (f32x4){0.f, 0.f, 0.f, 0.f};
        #pragma unroll
        for (int k = 0; k < 9; k++) {
            #pragma unroll
            for (int tc = 0; tc < 4; tc++) {
                bf16x8 bf = *(const bf16x8*)(krow + (tc * 16 + col) * KSTR + k * 32 + quad * 8);
                sf[tc] = __builtin_amdgcn_mfma_f32_16x16x32_bf16(qf[k], bf, sf[tc], 0, 0, 0);
            }
        }
        if (s0 == qb) {
            #pragma unroll
            for (int tc = 0; tc < 4; tc++)
                #pragma unroll
                for (int r = 0; r < 4; r++)
                    if (tc * 16 + col > wv * 16 + quad * 4 + r) sf[tc][r] = -1e30f;
        }
        float mnew[4], alpha[4];
        #pragma unroll
        for (int r = 0; r < 4; r++) {
            float mx = fmaxf(fmaxf(sf[0][r], sf[1][r]), fmaxf(sf[2][r], sf[3][r]));
            mx = fmaxf(mx, __shfl_xor(mx, 1));
            mx = fmaxf(mx, __shfl_xor(mx, 2));
            mx = fmaxf(mx, __shfl_xor(mx, 4));
            mx = fmaxf(mx, __shfl_xor(mx, 8));
            mnew[r] = fmaxf(m_i[r], mx);
            alpha[r] = __expf(m_i[r] - mnew[r]);
            m_i[r] = mnew[r];
        }
        float rsum[4];
        #pragma unroll
        for (int r = 0; r < 4; r++) {
            float s = 0.f;
            #pragma unroll
            for (int tc = 0; tc < 4; tc++) {
                float p = __expf(sf[tc][r] - mnew[r]);
                sf[tc][r] = p;
                s += p;
            }
            s += __shfl_xor(s, 1);
            s += __shfl_xor(s, 2);
            s += __shfl_xor(s, 4);
            s += __shfl_xor(s, 8);
            rsum[r] = s;
        }
        #pragma unroll
        for (int r = 0; r < 4; r++) l_i[r] = l_i[r] * alpha[r] + rsum[r];
        #pragma unroll
        for (int i = 0; i < 16; i++)
            #pragma unroll
            for (int r = 0; r < 4; r++) of[i][r] *= alpha[r];
        __syncthreads();
        #pragma unroll
        for (int tc = 0; tc < 4; tc++)
            #pragma unroll
            for (int r = 0; r < 4; r++)
                pbuf[(wv * 16 + quad * 4 + r) * PSTR + tc * 16 + col] = f2bf(sf[tc][r]);
        __syncthreads();
        bf16x8 pa[2];
        #pragma unroll
        for (int ks = 0; ks < 2; ks++)
            pa[ks] = *(const bf16x8*)(pbuf + (wv * 16 + col) * PSTR + ks * 32 + quad * 8);
        #pragma unroll
        for (int nt = 0; nt < 16; nt++) {
            #pragma unroll
            for (int ks = 0; ks < 2; ks++) {
                bf16x8 vb = *(const bf16x8*)(vt + (nt * 16 + col) * VSTR + ks * 32 + quad * 8);
                of[nt] = __builtin_amdgcn_mfma_f32_16x16x32_bf16(pa[ks], vb, of[nt], 0, 0, 0);
            }
        }
    }

    // ---------------- fused epilogue: o_bf[rows, h*64..] = (O/l) @ w_vc[h] ----------------
    __syncthreads();                       // all waves done with krow/vt
    ushort* obuf = lds;                    // 64 x OSTR (fits in krow region: 264 <= 296)
    ushort* wbuf = lds + 64 * KSTR;        // 64 x OSTR (fits in vt region)
    {
        float inv_l[4];
        #pragma unroll
        for (int r = 0; r < 4; r++) inv_l[r] = 1.0f / l_i[r];
        #pragma unroll
        for (int nt = 0; nt < 16; nt++)
            #pragma unroll
            for (int r = 0; r < 4; r++)
                obuf[(wv * 16 + quad * 4 + r) * OSTR + nt * 16 + col] = f2bf(of[nt][r] * inv_l[r]);
        // stage w_vct[h]: 64 rows x 256 k (32 KB), 8 x uint4 per thread, coalesced
        const ushort* wsrc = w_vct + (size_t)h * VDIM * KVLORA;
        #pragma unroll
        for (int i = 0; i < 8; i++) {
            int s = i * 256 + tid;
            int row = s >> 5, ch = s & 31;
            *(uint4*)(wbuf + row * OSTR + ch * 8) = *(const uint4*)(wsrc + (size_t)row * KVLORA + ch * 8);
        }
    }
    __syncthreads();
    f32x4 acc[4];
    #pragma unroll
    for (int j = 0; j < 4; j++) acc[j] = (f32x4){0.f, 0.f, 0.f, 0.f};
    #pragma unroll
    for (int ks = 0; ks < 8; ks++) {
        bf16x8 af = *(const bf16x8*)(obuf + (wv * 16 + col) * OSTR + ks * 32 + quad * 8);
        #pragma unroll
        for (int j = 0; j < 4; j++) {
            bf16x8 bw = *(const bf16x8*)(wbuf + (j * 16 + col) * OSTR + ks * 32 + quad * 8);
            acc[j] = __builtin_amdgcn_mfma_f32_16x16x32_bf16(af, bw, acc[j], 0, 0, 0);
        }
    }
    #pragma unroll
    for (int j = 0; j < 4; j++) {
        int gc = h * VDIM + j * 16 + col;
        #pragma unroll
        for (int r = 0; r < 4; r++)
            o_bf[(size_t)(qb + wv * 16 + quad * 4 + r) * HID + gc] = f2bf(acc[j][r]);
    }
}

extern "C" void kernel_launch(void* const* d_in, const int* in_sizes, int n_in,
                              void* d_out, int out_size, void* d_ws, size_t ws_size,
                              hipStream_t stream) {
    const int*   positions = (const int*)d_in[0];
    const float* hs    = (const float*)d_in[1];
    const float* w_qa  = (const float*)d_in[2];
    const float* g_qa  = (const float*)d_in[3];
    const float* w_qb  = (const float*)d_in[4];
    const float* w_kva = (const float*)d_in[5];
    const float* g_kva = (const float*)d_in[6];
    const float* w_kc  = (const float*)d_in[7];
    const float* w_vc  = (const float*)d_in[8];
    const float* w_o   = (const float*)d_in[9];
    float* out = (float*)d_out;

    float* ws    = (float*)d_ws;
    float* qa    = ws;                               // T*768
    float* q     = qa    + (size_t)TT * QLORA;       // T*3840
    float* kin   = q     + (size_t)TT * NH * QHD;    // T*288
    ushort* ub     = (ushort*)(kin + (size_t)TT * DQK);
    ushort* hs_bf  = ub;                             // T*2560
    ushort* qa_bf  = hs_bf  + (size_t)TT * HID;      // T*768
    ushort* o_bf   = qa_bf  + (size_t)TT * QLORA;    // T*2560
    ushort* kin_bf = o_bf   + (size_t)TT * HID;      // T*288
    ushort* qin_bf = kin_bf + (size_t)TT * DQK;      // T*40*288
    ushort* w_qa_t  = qin_bf + (size_t)TT * NH * DQK;       // 768*2560
    ushort* w_qb_t  = w_qa_t + (size_t)QLORA * HID;         // 3840*768
    ushort* w_kva_t = w_qb_t + (size_t)(NH * QHD) * QLORA;  // 288*2560
    ushort* w_o_t   = w_kva_t + (size_t)DQK * HID;          // 2560*2560
    ushort* w_vc_t  = w_o_t + (size_t)HID * HID;            // 40*64*256

    // ---- casts / transposes (independent of each other) ----
    cast_bf16<<<(TT * HID) / 1024, 256, 0, stream>>>(hs, hs_bf, TT * HID);
    transpose_cast<<<dim3(QLORA / 32, HID / 32), 256, 0, stream>>>(w_qa, w_qa_t, HID, QLORA);
    transpose_cast<<<dim3((NH * QHD) / 32, QLORA / 32), 256, 0, stream>>>(w_qb, w_qb_t, QLORA, NH * QHD);
    transpose_cast<<<dim3(DQK / 32, HID / 32), 256, 0, stream>>>(w_kva, w_kva_t, HID, DQK);
    transpose_cast<<<dim3(HID / 32, HID / 32), 256, 0, stream>>>(w_o, w_o_t, HID, HID);
    transpose_vc<<<dim3(VDIM / 32, KVLORA / 32, NH), 256, 0, stream>>>(w_vc, w_vc_t);

    // 1. qa = hs @ w_qa (MFMA, 128x64 tile: N=768 -> 192 blocks); RMS -> qa_bf
    gemm_bf16_n64<<<dim3(QLORA / 64, TT / 128), 256, 0, stream>>>(hs_bf, w_qa_t, qa, TT, QLORA, HID);
    rms_qa<<<TT, 256, 0, stream>>>(qa, g_qa, qa_bf);
    // 2. q = qa @ w_qb (MFMA)
    gemm_bf16<<<dim3((NH * QHD) / 128, TT / 128), 256, 0, stream>>>(qa_bf, w_qb_t, q, TT, NH * QHD, QLORA);
    // 3. kin = hs @ w_kva (MFMA, 128x64 tile: N=288 -> 80 blocks); RMS+RoPE -> kin_bf
    gemm_bf16_n64<<<dim3((DQK + 63) / 64, TT / 128), 256, 0, stream>>>(hs_bf, w_kva_t, kin, TT, DQK, HID);
    kin_post<<<TT, 256, 0, stream>>>(kin, g_kva, positions, kin_bf);
    // 4. qin_bf = [q_nope @ w_kc[h] | rope(q_pe)] * scale
    build_qin<<<dim3(TT / QTB, NH), 256, 0, stream>>>(q, w_kc, positions, qin_bf);
    // 5. flash MFMA attention with fused w_vc projection -> o_bf directly
    flash_attn<<<dim3(TT / 64, NH), 256, 0, stream>>>(qin_bf, kin_bf, w_vc_t, o_bf);
    // 6. out = o_bf @ w_o (MFMA)
    gemm_bf16<<<dim3(HID / 128, TT / 128), 256, 0, stream>>>(o_bf, w_o_t, out, TT, HID, HID);
}